// Round 9
// baseline (183.522 us; speedup 1.0000x reference)
//
#include <hip/hip_runtime.h>

#define B_  2
#define S_  2048
#define E_  1024
#define H_  16
#define D_  64
#define NGLOB 2
#define NRAND 3
#define WIN 3

typedef __bf16 bf16x8 __attribute__((ext_vector_type(8)));
typedef float  f32x4  __attribute__((ext_vector_type(4)));

__device__ __forceinline__ unsigned short f2bf(float f) {
    unsigned u = __builtin_bit_cast(unsigned, f);
    unsigned r = u + 0x7FFFu + ((u >> 16) & 1u);   // RNE
    return (unsigned short)(r >> 16);
}
__device__ __forceinline__ float bf2f(unsigned short u) {
    return __builtin_bit_cast(float, (unsigned)u << 16);
}

// async global->LDS 16B DMA. LDS dest is wave-uniform base + lane*16.
__device__ __forceinline__ void g2l16(const unsigned short* g, unsigned short* l) {
    __builtin_amdgcn_global_load_lds(
        (const __attribute__((address_space(1))) unsigned*)g,
        (__attribute__((address_space(3))) unsigned*)l, 16, 0, 0);
}

// ---------------- fused fp32 -> bf16 conversion for x + 4 weights ----------------
__global__ __launch_bounds__(256)
void convert_all(const float* __restrict__ x,  const float* __restrict__ qw,
                 const float* __restrict__ kw, const float* __restrict__ vw,
                 const float* __restrict__ ow,
                 unsigned short* __restrict__ xb, unsigned short* __restrict__ wqkv,
                 unsigned short* __restrict__ wo) {
    const int XN = (B_ * S_ * E_) / 4;      // 1048576
    const int WN = (E_ * E_) / 4;           // 262144
    int i = blockIdx.x * blockDim.x + threadIdx.x;
    int r, loc;
    if (i < XN) { r = 0; loc = i; }
    else        { int j = i - XN; r = 1 + (j >> 18); loc = j & (WN - 1); }
    const float* src = r == 0 ? x : r == 1 ? qw : r == 2 ? kw : r == 3 ? vw : ow;
    float4 f = ((const float4*)src)[loc];
    ushort4 u;
    u.x = f2bf(f.x); u.y = f2bf(f.y); u.z = f2bf(f.z); u.w = f2bf(f.w);
    ushort4* dst = r == 0 ? (ushort4*)xb : r == 4 ? (ushort4*)wo
                 : (ushort4*)wqkv + (size_t)(r - 1) * WN;
    dst[loc] = u;
}

// ---------------- QKV GEMM: BK=64, XOR-swizzled LDS ----------------
// (256,2): (256,3)'s 170-VGPR cap spilled the K-loop (r8: +8us). Let the
// allocator breathe; 2 blocks/CU resident is enough with 512-block grid.
__global__ __launch_bounds__(256, 2)
void gemm_qkv(const unsigned short* __restrict__ A,  // [M][K] bf16
              const unsigned short* __restrict__ W,  // [N][K] bf16
              const float* __restrict__ b0, const float* __restrict__ b1,
              const float* __restrict__ b2,
              unsigned short* __restrict__ Cb, int M, int N, int K) {
    __shared__ unsigned short sA[128 * 64];   // 16 KB
    __shared__ unsigned short sB[128 * 64];   // 16 KB
    const int t = threadIdx.x;
    const int lane = t & 63;
    const int wave = t >> 6;
    const int wm = wave >> 1, wn = wave & 1;
    const int lq = lane >> 4;
    const int lr = lane & 15;
    const int bm = blockIdx.x * 128;
    const int bn = blockIdx.y * 128;

    f32x4 acc[4][4] = {};

    for (int k0 = 0; k0 < K; k0 += 64) {
        const unsigned short* Abase = A + (size_t)bm * K + k0;
        const unsigned short* Wbase = W + (size_t)bn * K + k0;
        #pragma unroll
        for (int j = 0; j < 4; ++j) {
            int c = j * 256 + t;                  // chunk 0..1023
            int row = c >> 3, cc = c & 7;
            int gcol = ((cc ^ (row & 7)) << 3);   // swizzled source col
            int dst = j * 2048 + wave * 512;      // wave-uniform elem offset
            g2l16(Abase + (size_t)row * K + gcol, sA + dst);
            g2l16(Wbase + (size_t)row * K + gcol, sB + dst);
        }
        __syncthreads();

        #pragma unroll
        for (int ks = 0; ks < 2; ++ks) {
            const int sw = (((ks << 2) + lq) ^ (lr & 7)) << 3;
            bf16x8 af[4], bfr[4];
            #pragma unroll
            for (int i = 0; i < 4; ++i)
                af[i] = *(const bf16x8*)&sA[(wm * 64 + i * 16 + lr) * 64 + sw];
            #pragma unroll
            for (int j = 0; j < 4; ++j)
                bfr[j] = *(const bf16x8*)&sB[(wn * 64 + j * 16 + lr) * 64 + sw];
            #pragma unroll
            for (int i = 0; i < 4; ++i)
                #pragma unroll
                for (int j = 0; j < 4; ++j)
                    acc[i][j] = __builtin_amdgcn_mfma_f32_16x16x32_bf16(af[i], bfr[j], acc[i][j], 0, 0, 0);
        }
        __syncthreads();
    }

    #pragma unroll
    for (int i = 0; i < 4; ++i) {
        int row0 = bm + wm * 64 + i * 16 + lq * 4;
        #pragma unroll
        for (int j = 0; j < 4; ++j) {
            int col = bn + wn * 64 + j * 16 + lr;
            const float* bp = col < E_ ? b0 : (col < 2 * E_ ? b1 : b2);
            float bv = bp[col & (E_ - 1)];
            #pragma unroll
            for (int r = 0; r < 4; ++r)
                Cb[(size_t)(row0 + r) * N + col] = f2bf(acc[i][j][r] + bv);
        }
    }
}

// ---------------- O GEMM: 128x64 tile, BK=32 ----------------
#define TM 128
#define TK 32
__global__ __launch_bounds__(256, 2)
void gemm_bt64(const unsigned short* __restrict__ A,
               const unsigned short* __restrict__ W,
               const float* __restrict__ bias,
               float* __restrict__ Cf, int M, int N, int K) {
    __shared__ unsigned short sA[TM * TK];   // 8 KB
    __shared__ unsigned short sB[64 * TK];   // 4 KB
    const int t = threadIdx.x;
    const int lane = t & 63;
    const int wave = t >> 6;
    const int lq = lane >> 4;
    const int lr = lane & 15;
    const int bm = blockIdx.x * TM;
    const int bn = blockIdx.y * 64;

    f32x4 acc[2][4] = {};

    for (int k0 = 0; k0 < K; k0 += TK) {
        const unsigned short* Abase = A + (size_t)bm * K + k0;
        const unsigned short* Wbase = W + (size_t)bn * K + k0;
        #pragma unroll
        for (int j = 0; j < 2; ++j) {
            int chunk = j * 256 + t;
            int row = chunk >> 2, col = (chunk & 3) * 8;
            int wbase = j * 2048 + wave * 512;
            g2l16(Abase + (size_t)row * K + col, sA + wbase);
        }
        {
            int row = t >> 2, col = (t & 3) * 8;
            g2l16(Wbase + (size_t)row * K + col, sB + wave * 512);
        }
        __syncthreads();

        bf16x8 af[2], bfr[4];
        #pragma unroll
        for (int i = 0; i < 2; ++i)
            af[i] = *(const bf16x8*)&sA[(wave * 32 + i * 16 + lr) * TK + lq * 8];
        #pragma unroll
        for (int j = 0; j < 4; ++j)
            bfr[j] = *(const bf16x8*)&sB[(j * 16 + lr) * TK + lq * 8];
        #pragma unroll
        for (int i = 0; i < 2; ++i)
            #pragma unroll
            for (int j = 0; j < 4; ++j)
                acc[i][j] = __builtin_amdgcn_mfma_f32_16x16x32_bf16(af[i], bfr[j], acc[i][j], 0, 0, 0);
        __syncthreads();
    }

    #pragma unroll
    for (int i = 0; i < 2; ++i) {
        int row0 = bm + wave * 32 + i * 16 + lq * 4;
        #pragma unroll
        for (int j = 0; j < 4; ++j) {
            int col = bn + j * 16 + lr;
            float bv = bias[col];
            #pragma unroll
            for (int r = 0; r < 4; ++r)
                Cf[(size_t)(row0 + r) * N + col] = acc[i][j][r] + bv;
        }
    }
}

// ---------------- fused: sparse rows (wave-per-row) + global-row scores ----------------
// grid = 1024 (sparse, XCD-swizzled) + 512 (gattn score chunks; seg==0 zeroes gacc+cnt)
__global__ __launch_bounds__(256)
void attn_fused(const unsigned short* __restrict__ qkv,
                const int* __restrict__ rnd,
                float* __restrict__ gsc, float* __restrict__ gacc,
                int* __restrict__ cnt,
                unsigned short* __restrict__ attn) {
    const int NB = B_ * (S_ - 2);     // 4092
    int t = threadIdx.x;

    if (blockIdx.x >= 1024) {
        // ---- global-row score chunk ----
        int bid2 = blockIdx.x - 1024;         // [0,512)
        int tup = bid2 >> 3, seg = bid2 & 7;
        int b = tup >> 5, i = (tup >> 4) & 1, h = tup & 15;
        __shared__ float qs[D_];
        if (t < D_) qs[t] = bf2f(qkv[(size_t)(b * S_ + i) * 3072 + h * D_ + t]);
        if (seg == 0) {
            if (t < D_) gacc[tup * D_ + t] = 0.f;
            if (t == D_) cnt[tup] = 0;
        }
        __syncthreads();
        int c = seg * 256 + t;
        const bf16x8* kp = (const bf16x8*)(qkv + (size_t)(b * S_ + c) * 3072 + E_ + h * D_);
        float s = 0.f;
        #pragma unroll
        for (int w = 0; w < 8; ++w) {
            bf16x8 kv = kp[w];
            #pragma unroll
            for (int j = 0; j < 8; ++j) s += qs[w * 8 + j] * (float)kv[j];
        }
        gsc[(size_t)tup * S_ + c] = s * 0.125f;
        return;
    }

    // ---- sparse rows: one wave per row ----
    int bidx = (blockIdx.x & 7) * 128 + (blockIdx.x >> 3);   // XCD swizzle
    int w = t >> 6, l = t & 63;
    int row = bidx * 4 + w;
    bool valid = row < NB;
    int b = row / (S_ - 2);
    int i = row % (S_ - 2) + 2;
    if (!valid) { b = 0; i = 2; }

    __shared__ int   cols_s[4][12];
    __shared__ int   ncol_sh[4];
    __shared__ float pr_s[4][16 * 13 + 3];

    const bf16x8* qp = (const bf16x8*)(qkv + (size_t)(b * S_ + i) * 3072);
    bf16x8 q0 = qp[l * 2], q1 = qp[l * 2 + 1];
    float qreg[16];
    #pragma unroll
    for (int j = 0; j < 8; ++j) { qreg[j] = (float)q0[j]; qreg[8 + j] = (float)q1[j]; }

    if (l == 0) {
        int* cols = cols_s[w];
        int n = 0;
        cols[n++] = 0; cols[n++] = 1;
        int lo = i - WIN; if (lo < NGLOB) lo = NGLOB;
        int hi = i + WIN; if (hi > S_ - 1) hi = S_ - 1;
        for (int j = lo; j <= hi; ++j) cols[n++] = j;
        for (int r = 0; r < NRAND; ++r) {
            int c = rnd[i * NRAND + r];
            bool dup = false;
            for (int q = 0; q < n; ++q) dup = dup || (cols[q] == c);
            if (!dup) cols[n++] = c;
        }
        ncol_sh[w] = n;
        for (int q = n; q < 12; ++q) cols[q] = 0;
    }
    __syncthreads();
    const int n = ncol_sh[w];
    const int h4 = l >> 2;

    float sco[12];
    #pragma unroll
    for (int c = 0; c < 12; ++c) {
        const bf16x8* kp = (const bf16x8*)(qkv + (size_t)(b * S_ + cols_s[w][c]) * 3072 + E_);
        bf16x8 k0 = kp[l * 2], k1 = kp[l * 2 + 1];
        float s = 0.f;
        #pragma unroll
        for (int j = 0; j < 8; ++j) s += qreg[j] * (float)k0[j] + qreg[8 + j] * (float)k1[j];
        s += __shfl_xor(s, 1);
        s += __shfl_xor(s, 2);
        sco[c] = (c < n) ? s * 0.125f : -1e30f;
    }

    if ((l & 3) == 0) {
        float m = -1e30f;
        #pragma unroll
        for (int c = 0; c < 12; ++c) m = fmaxf(m, sco[c]);
        float sum = 0.f;
        #pragma unroll
        for (int c = 0; c < 12; ++c) { float e = __expf(sco[c] - m); sco[c] = e; sum += e; }
        float inv = 1.f / sum;
        #pragma unroll
        for (int c = 0; c < 12; ++c) pr_s[w][h4 * 13 + c] = sco[c] * inv;
    }
    __syncthreads();

    float o[16] = {};
    #pragma unroll
    for (int c = 0; c < 12; ++c) {
        float p = pr_s[w][h4 * 13 + c];
        const bf16x8* vp = (const bf16x8*)(qkv + (size_t)(b * S_ + cols_s[w][c]) * 3072 + 2 * E_);
        bf16x8 v0 = vp[l * 2], v1 = vp[l * 2 + 1];
        #pragma unroll
        for (int j = 0; j < 8; ++j) { o[j] += p * (float)v0[j]; o[8 + j] += p * (float)v1[j]; }
    }

    if (valid) {
        ushort4 u0, u1, u2, u3;
        u0.x = f2bf(o[0]);  u0.y = f2bf(o[1]);  u0.z = f2bf(o[2]);  u0.w = f2bf(o[3]);
        u1.x = f2bf(o[4]);  u1.y = f2bf(o[5]);  u1.z = f2bf(o[6]);  u1.w = f2bf(o[7]);
        u2.x = f2bf(o[8]);  u2.y = f2bf(o[9]);  u2.z = f2bf(o[10]); u2.w = f2bf(o[11]);
        u3.x = f2bf(o[12]); u3.y = f2bf(o[13]); u3.z = f2bf(o[14]); u3.w = f2bf(o[15]);
        ushort4* op = (ushort4*)(attn + (size_t)(b * S_ + i) * E_ + l * 16);
        op[0] = u0; op[1] = u1; op[2] = u2; op[3] = u3;
    }
}

// ---------------- global-row PV: inline softmax + counter-based finalize ----------------
__global__ __launch_bounds__(256)
void gattn_pv(const unsigned short* __restrict__ qkv, const float* __restrict__ gsc,
              float* __restrict__ gacc, int* __restrict__ cnt,
              unsigned short* __restrict__ attn) {
    int tup = blockIdx.x, chunk = blockIdx.y;
    int b = tup >> 5, i = (tup >> 4) & 1, h = tup & 15;
    int t = threadIdx.x, w = t >> 6, d = t & 63;
    __shared__ float ps[S_];          // probs, 8 KB
    __shared__ float red[4];
    __shared__ float redv[4][D_];
    __shared__ int   last_s;
    const float* sc = gsc + (size_t)tup * S_;

    float vals[8];
    float m = -1e30f;
    #pragma unroll
    for (int k = 0; k < 8; ++k) { vals[k] = sc[t + 256 * k]; m = fmaxf(m, vals[k]); }
    #pragma unroll
    for (int o = 32; o; o >>= 1) m = fmaxf(m, __shfl_down(m, o));
    if ((t & 63) == 0) red[t >> 6] = m;
    __syncthreads();
    m = fmaxf(fmaxf(red[0], red[1]), fmaxf(red[2], red[3]));
    __syncthreads();
    float sum = 0.f;
    #pragma unroll
    for (int k = 0; k < 8; ++k) { float e = __expf(vals[k] - m); vals[k] = e; sum += e; }
    #pragma unroll
    for (int o = 32; o; o >>= 1) sum += __shfl_down(sum, o);
    if ((t & 63) == 0) red[t >> 6] = sum;
    __syncthreads();
    float inv = 1.f / (red[0] + red[1] + red[2] + red[3]);
    #pragma unroll
    for (int k = 0; k < 8; ++k) ps[t + 256 * k] = vals[k] * inv;
    __syncthreads();

    const float* P = ps + chunk * 256 + w * 64;
    float acc = 0.f;
    #pragma unroll 4
    for (int k = 0; k < 64; ++k) {
        int c = chunk * 256 + w * 64 + k;
        acc += P[k] * bf2f(qkv[(size_t)(b * S_ + c) * 3072 + 2 * E_ + h * D_ + d]);
    }
    redv[w][d] = acc;
    __syncthreads();
    if (w == 0) {
        atomicAdd(&gacc[tup * D_ + d], redv[0][d] + redv[1][d] + redv[2][d] + redv[3][d]);
        __threadfence();                    // adds visible before counter bump
        if (d == 0) last_s = (atomicAdd(&cnt[tup], 1) == 7);
    }
    __syncthreads();
    if (last_s) {
        __threadfence();
        if (t < D_) {
            float v = atomicAdd(&gacc[tup * D_ + t], 0.0f);   // coherent read
            attn[(size_t)(b * S_ + i) * E_ + h * D_ + t] = f2bf(v);
        }
    }
}

extern "C" void kernel_launch(void* const* d_in, const int* in_sizes, int n_in,
                              void* d_out, int out_size, void* d_ws, size_t ws_size,
                              hipStream_t stream) {
    const float* x   = (const float*)d_in[0];
    const int*   rnd = (const int*)d_in[1];
    const float* qw  = (const float*)d_in[2];
    const float* qb  = (const float*)d_in[3];
    const float* kw  = (const float*)d_in[4];
    const float* kb  = (const float*)d_in[5];
    const float* vw  = (const float*)d_in[6];
    const float* vb  = (const float*)d_in[7];
    const float* ow  = (const float*)d_in[8];
    const float* ob  = (const float*)d_in[9];
    float* out = (float*)d_out;

    char* ws = (char*)d_ws;
    unsigned short* xb    = (unsigned short*)(ws);                       // 8 MB (dead after QKV GEMM)
    unsigned short* wqkv  = (unsigned short*)(ws + 8388608);             // 6 MB
    unsigned short* wo    = (unsigned short*)(ws + 14680064);            // 2 MB
    unsigned short* qkv   = (unsigned short*)(ws + 16777216);            // 24 MB
    unsigned short* attn  = (unsigned short*)(ws + 41943040);            // 8 MB
    float*          gsc   = (float*)(ws);                                // 512 KB (overlaps dead xb)
    float*          gacc  = (float*)(ws + 524288);                       // 16 KB
    int*            cnt   = (int*)(ws + 524288 + 16384);                 // 256 B

    const int M = B_ * S_;   // 4096

    {
        int total4 = (M * E_ + 4 * E_ * E_) / 4;
        convert_all<<<total4 / 256, 256, 0, stream>>>(x, qw, kw, vw, ow, xb, wqkv, wo);
    }

    // QKV GEMM: [4096][3072] bf16, BK=64 swizzled
    {
        dim3 grid(M / 128, 3 * E_ / 128);
        gemm_qkv<<<grid, 256, 0, stream>>>(xb, wqkv, qb, kb, vb, qkv, M, 3 * E_, E_);
    }

    // sparse rows + global-row scores (+ gacc/cnt zero), one dispatch
    attn_fused<<<1024 + 512, 256, 0, stream>>>(qkv, rnd, gsc, gacc, cnt, attn);

    // global-row PV (inline softmax + counter finalize)
    gattn_pv<<<dim3(B_ * NGLOB * H_, S_ / 256), 256, 0, stream>>>(qkv, gsc, gacc, cnt, attn);

    // O GEMM -> fp32 out
    {
        dim3 grid(M / TM, E_ / 64);
        gemm_bt64<<<grid, 256, 0, stream>>>(attn, wo, ob, out, M, E_, E_);
    }
}

// Round 11
// 173.315 us; speedup vs baseline: 1.0589x; 1.0589x over previous
//
#include <hip/hip_runtime.h>

#define B_  2
#define S_  2048
#define E_  1024
#define H_  16
#define D_  64
#define NGLOB 2
#define NRAND 3
#define WIN 3

typedef __bf16 bf16x8 __attribute__((ext_vector_type(8)));
typedef float  f32x4  __attribute__((ext_vector_type(4)));

__device__ __forceinline__ unsigned short f2bf(float f) {
    unsigned u = __builtin_bit_cast(unsigned, f);
    unsigned r = u + 0x7FFFu + ((u >> 16) & 1u);   // RNE
    return (unsigned short)(r >> 16);
}
__device__ __forceinline__ float bf2f(unsigned short u) {
    return __builtin_bit_cast(float, (unsigned)u << 16);
}

// async global->LDS 16B DMA. LDS dest is wave-uniform base + lane*16.
__device__ __forceinline__ void g2l16(const unsigned short* g, unsigned short* l) {
    __builtin_amdgcn_global_load_lds(
        (const __attribute__((address_space(1))) unsigned*)g,
        (__attribute__((address_space(3))) unsigned*)l, 16, 0, 0);
}

// ---------------- fused fp32 -> bf16 conversion for x + 4 weights ----------------
__global__ __launch_bounds__(256)
void convert_all(const float* __restrict__ x,  const float* __restrict__ qw,
                 const float* __restrict__ kw, const float* __restrict__ vw,
                 const float* __restrict__ ow,
                 unsigned short* __restrict__ xb, unsigned short* __restrict__ wqkv,
                 unsigned short* __restrict__ wo) {
    const int XN = (B_ * S_ * E_) / 4;      // 1048576
    const int WN = (E_ * E_) / 4;           // 262144
    int i = blockIdx.x * blockDim.x + threadIdx.x;
    int r, loc;
    if (i < XN) { r = 0; loc = i; }
    else        { int j = i - XN; r = 1 + (j >> 18); loc = j & (WN - 1); }
    const float* src = r == 0 ? x : r == 1 ? qw : r == 2 ? kw : r == 3 ? vw : ow;
    float4 f = ((const float4*)src)[loc];
    ushort4 u;
    u.x = f2bf(f.x); u.y = f2bf(f.y); u.z = f2bf(f.z); u.w = f2bf(f.w);
    ushort4* dst = r == 0 ? (ushort4*)xb : r == 4 ? (ushort4*)wo
                 : (ushort4*)wqkv + (size_t)(r - 1) * WN;
    dst[loc] = u;
}

// ---------------- QKV GEMM: BK=64, XOR-swizzled LDS (R7-proven) ----------------
__global__ __launch_bounds__(256, 2)
void gemm_qkv(const unsigned short* __restrict__ A,  // [M][K] bf16
              const unsigned short* __restrict__ W,  // [N][K] bf16
              const float* __restrict__ b0, const float* __restrict__ b1,
              const float* __restrict__ b2,
              unsigned short* __restrict__ Cb, int M, int N, int K) {
    __shared__ unsigned short sA[128 * 64];   // 16 KB
    __shared__ unsigned short sB[128 * 64];   // 16 KB
    const int t = threadIdx.x;
    const int lane = t & 63;
    const int wave = t >> 6;
    const int wm = wave >> 1, wn = wave & 1;
    const int lq = lane >> 4;
    const int lr = lane & 15;
    const int bm = blockIdx.x * 128;
    const int bn = blockIdx.y * 128;

    f32x4 acc[4][4] = {};

    for (int k0 = 0; k0 < K; k0 += 64) {
        const unsigned short* Abase = A + (size_t)bm * K + k0;
        const unsigned short* Wbase = W + (size_t)bn * K + k0;
        #pragma unroll
        for (int j = 0; j < 4; ++j) {             // 1024 chunks each
            int c = j * 256 + t;
            int row = c >> 3, cc = c & 7;
            int gcol = ((cc ^ (row & 7)) << 3);   // swizzled source col
            int dst = j * 2048 + wave * 512;      // wave-uniform elem offset
            g2l16(Abase + (size_t)row * K + gcol, sA + dst);
            g2l16(Wbase + (size_t)row * K + gcol, sB + dst);
        }
        __syncthreads();

        #pragma unroll
        for (int ks = 0; ks < 2; ++ks) {
            const int sw = (((ks << 2) + lq) ^ (lr & 7)) << 3;
            bf16x8 af[4], bfr[4];
            #pragma unroll
            for (int i = 0; i < 4; ++i)
                af[i] = *(const bf16x8*)&sA[(wm * 64 + i * 16 + lr) * 64 + sw];
            #pragma unroll
            for (int j = 0; j < 4; ++j)
                bfr[j] = *(const bf16x8*)&sB[(wn * 64 + j * 16 + lr) * 64 + sw];
            #pragma unroll
            for (int i = 0; i < 4; ++i)
                #pragma unroll
                for (int j = 0; j < 4; ++j)
                    acc[i][j] = __builtin_amdgcn_mfma_f32_16x16x32_bf16(af[i], bfr[j], acc[i][j], 0, 0, 0);
        }
        __syncthreads();
    }

    #pragma unroll
    for (int i = 0; i < 4; ++i) {
        int row0 = bm + wm * 64 + i * 16 + lq * 4;
        #pragma unroll
        for (int j = 0; j < 4; ++j) {
            int col = bn + wn * 64 + j * 16 + lr;
            const float* bp = col < E_ ? b0 : (col < 2 * E_ ? b1 : b2);
            float bv = bp[col & (E_ - 1)];
            #pragma unroll
            for (int r = 0; r < 4; ++r)
                Cb[(size_t)(row0 + r) * N + col] = f2bf(acc[i][j][r] + bv);
        }
    }
}

// ---------------- O GEMM: 128x64 tile, BK=64 XOR-swizzled (staging fixed) ----------------
// A tile 128x64 = 1024 chunks (j<4); B tile 64x64 = 512 chunks (j<2).
__global__ __launch_bounds__(256, 2)
void gemm_o64(const unsigned short* __restrict__ A,
              const unsigned short* __restrict__ W,
              const float* __restrict__ bias,
              float* __restrict__ Cf, int M, int N, int K) {
    __shared__ unsigned short sA[128 * 64];   // 16 KB
    __shared__ unsigned short sB[64 * 64];    // 8 KB
    const int t = threadIdx.x;
    const int lane = t & 63;
    const int wave = t >> 6;
    const int lq = lane >> 4;
    const int lr = lane & 15;
    const int bm = blockIdx.x * 128;
    const int bn = blockIdx.y * 64;

    f32x4 acc[2][4] = {};

    for (int k0 = 0; k0 < K; k0 += 64) {
        const unsigned short* Abase = A + (size_t)bm * K + k0;
        const unsigned short* Wbase = W + (size_t)bn * K + k0;
        #pragma unroll
        for (int j = 0; j < 4; ++j) {           // A: 1024 chunks
            int c = j * 256 + t;
            int row = c >> 3, cc = c & 7;
            int gcol = ((cc ^ (row & 7)) << 3);
            int dst = j * 2048 + wave * 512;
            g2l16(Abase + (size_t)row * K + gcol, sA + dst);
        }
        #pragma unroll
        for (int j = 0; j < 2; ++j) {           // B: 512 chunks
            int c = j * 256 + t;
            int row = c >> 3, cc = c & 7;
            int gcol = ((cc ^ (row & 7)) << 3);
            int dst = j * 2048 + wave * 512;
            g2l16(Wbase + (size_t)row * K + gcol, sB + dst);
        }
        __syncthreads();

        #pragma unroll
        for (int ks = 0; ks < 2; ++ks) {
            const int sw = (((ks << 2) + lq) ^ (lr & 7)) << 3;
            bf16x8 af[2], bfr[4];
            #pragma unroll
            for (int i = 0; i < 2; ++i)
                af[i] = *(const bf16x8*)&sA[(wave * 32 + i * 16 + lr) * 64 + sw];
            #pragma unroll
            for (int j = 0; j < 4; ++j)
                bfr[j] = *(const bf16x8*)&sB[(j * 16 + lr) * 64 + sw];
            #pragma unroll
            for (int i = 0; i < 2; ++i)
                #pragma unroll
                for (int j = 0; j < 4; ++j)
                    acc[i][j] = __builtin_amdgcn_mfma_f32_16x16x32_bf16(af[i], bfr[j], acc[i][j], 0, 0, 0);
        }
        __syncthreads();
    }

    #pragma unroll
    for (int i = 0; i < 2; ++i) {
        int row0 = bm + wave * 32 + i * 16 + lq * 4;
        #pragma unroll
        for (int j = 0; j < 4; ++j) {
            int col = bn + j * 16 + lr;
            float bv = bias[col];
            #pragma unroll
            for (int r = 0; r < 4; ++r)
                Cf[(size_t)(row0 + r) * N + col] = acc[i][j][r] + bv;
        }
    }
}

// ---------------- fused: sparse rows (wave-per-row) + global-row scores ----------------
// grid = 1024 (sparse, XCD-swizzled) + 512 (gattn score chunks; seg==0 zeroes gacc)
__global__ __launch_bounds__(256)
void attn_fused(const unsigned short* __restrict__ qkv,
                const int* __restrict__ rnd,
                float* __restrict__ gsc, float* __restrict__ gacc,
                unsigned short* __restrict__ attn) {
    const int NB = B_ * (S_ - 2);     // 4092
    int t = threadIdx.x;

    if (blockIdx.x >= 1024) {
        // ---- global-row score chunk ----
        int bid2 = blockIdx.x - 1024;         // [0,512)
        int tup = bid2 >> 3, seg = bid2 & 7;
        int b = tup >> 5, i = (tup >> 4) & 1, h = tup & 15;
        __shared__ float qs[D_];
        if (t < D_) qs[t] = bf2f(qkv[(size_t)(b * S_ + i) * 3072 + h * D_ + t]);
        if (seg == 0 && t < D_) gacc[tup * D_ + t] = 0.f;
        __syncthreads();
        int c = seg * 256 + t;
        const bf16x8* kp = (const bf16x8*)(qkv + (size_t)(b * S_ + c) * 3072 + E_ + h * D_);
        float s = 0.f;
        #pragma unroll
        for (int w = 0; w < 8; ++w) {
            bf16x8 kv = kp[w];
            #pragma unroll
            for (int j = 0; j < 8; ++j) s += qs[w * 8 + j] * (float)kv[j];
        }
        gsc[(size_t)tup * S_ + c] = s * 0.125f;
        return;
    }

    // ---- sparse rows: one wave per row ----
    int bidx = (blockIdx.x & 7) * 128 + (blockIdx.x >> 3);   // XCD swizzle
    int w = t >> 6, l = t & 63;
    int row = bidx * 4 + w;
    bool valid = row < NB;
    int b = row / (S_ - 2);
    int i = row % (S_ - 2) + 2;
    if (!valid) { b = 0; i = 2; }

    __shared__ int   cols_s[4][12];
    __shared__ int   ncol_sh[4];
    __shared__ float pr_s[4][16 * 13 + 3];

    const bf16x8* qp = (const bf16x8*)(qkv + (size_t)(b * S_ + i) * 3072);
    bf16x8 q0 = qp[l * 2], q1 = qp[l * 2 + 1];
    float qreg[16];
    #pragma unroll
    for (int j = 0; j < 8; ++j) { qreg[j] = (float)q0[j]; qreg[8 + j] = (float)q1[j]; }

    if (l == 0) {
        int* cols = cols_s[w];
        int n = 0;
        cols[n++] = 0; cols[n++] = 1;
        int lo = i - WIN; if (lo < NGLOB) lo = NGLOB;
        int hi = i + WIN; if (hi > S_ - 1) hi = S_ - 1;
        for (int j = lo; j <= hi; ++j) cols[n++] = j;
        for (int r = 0; r < NRAND; ++r) {
            int c = rnd[i * NRAND + r];
            bool dup = false;
            for (int q = 0; q < n; ++q) dup = dup || (cols[q] == c);
            if (!dup) cols[n++] = c;
        }
        ncol_sh[w] = n;
        for (int q = n; q < 12; ++q) cols[q] = 0;
    }
    __syncthreads();
    const int n = ncol_sh[w];
    const int h4 = l >> 2;

    float sco[12];
    #pragma unroll
    for (int c = 0; c < 12; ++c) {
        const bf16x8* kp = (const bf16x8*)(qkv + (size_t)(b * S_ + cols_s[w][c]) * 3072 + E_);
        bf16x8 k0 = kp[l * 2], k1 = kp[l * 2 + 1];
        float s = 0.f;
        #pragma unroll
        for (int j = 0; j < 8; ++j) s += qreg[j] * (float)k0[j] + qreg[8 + j] * (float)k1[j];
        s += __shfl_xor(s, 1);
        s += __shfl_xor(s, 2);
        sco[c] = (c < n) ? s * 0.125f : -1e30f;
    }

    if ((l & 3) == 0) {
        float m = -1e30f;
        #pragma unroll
        for (int c = 0; c < 12; ++c) m = fmaxf(m, sco[c]);
        float sum = 0.f;
        #pragma unroll
        for (int c = 0; c < 12; ++c) { float e = __expf(sco[c] - m); sco[c] = e; sum += e; }
        float inv = 1.f / sum;
        #pragma unroll
        for (int c = 0; c < 12; ++c) pr_s[w][h4 * 13 + c] = sco[c] * inv;
    }
    __syncthreads();

    float o[16] = {};
    #pragma unroll
    for (int c = 0; c < 12; ++c) {
        float p = pr_s[w][h4 * 13 + c];
        const bf16x8* vp = (const bf16x8*)(qkv + (size_t)(b * S_ + cols_s[w][c]) * 3072 + 2 * E_);
        bf16x8 v0 = vp[l * 2], v1 = vp[l * 2 + 1];
        #pragma unroll
        for (int j = 0; j < 8; ++j) { o[j] += p * (float)v0[j]; o[8 + j] += p * (float)v1[j]; }
    }

    if (valid) {
        ushort4 u0, u1, u2, u3;
        u0.x = f2bf(o[0]);  u0.y = f2bf(o[1]);  u0.z = f2bf(o[2]);  u0.w = f2bf(o[3]);
        u1.x = f2bf(o[4]);  u1.y = f2bf(o[5]);  u1.z = f2bf(o[6]);  u1.w = f2bf(o[7]);
        u2.x = f2bf(o[8]);  u2.y = f2bf(o[9]);  u2.z = f2bf(o[10]); u2.w = f2bf(o[11]);
        u3.x = f2bf(o[12]); u3.y = f2bf(o[13]); u3.z = f2bf(o[14]); u3.w = f2bf(o[15]);
        ushort4* op = (ushort4*)(attn + (size_t)(b * S_ + i) * E_ + l * 16);
        op[0] = u0; op[1] = u1; op[2] = u2; op[3] = u3;
    }
}

// ---------------- global-row PV with inline softmax (no fences — R7 form) ----------------
__global__ __launch_bounds__(256)
void gattn_pv(const unsigned short* __restrict__ qkv, const float* __restrict__ gsc,
              float* __restrict__ gacc) {
    int tup = blockIdx.x, chunk = blockIdx.y;
    int b = tup >> 5, h = tup & 15;
    int t = threadIdx.x, w = t >> 6, d = t & 63;
    __shared__ float ps[S_];          // probs, 8 KB
    __shared__ float red[4];
    __shared__ float redv[4][D_];
    const float* sc = gsc + (size_t)tup * S_;

    float vals[8];
    float m = -1e30f;
    #pragma unroll
    for (int k = 0; k < 8; ++k) { vals[k] = sc[t + 256 * k]; m = fmaxf(m, vals[k]); }
    #pragma unroll
    for (int o = 32; o; o >>= 1) m = fmaxf(m, __shfl_down(m, o));
    if ((t & 63) == 0) red[t >> 6] = m;
    __syncthreads();
    m = fmaxf(fmaxf(red[0], red[1]), fmaxf(red[2], red[3]));
    __syncthreads();
    float sum = 0.f;
    #pragma unroll
    for (int k = 0; k < 8; ++k) { float e = __expf(vals[k] - m); vals[k] = e; sum += e; }
    #pragma unroll
    for (int o = 32; o; o >>= 1) sum += __shfl_down(sum, o);
    if ((t & 63) == 0) red[t >> 6] = sum;
    __syncthreads();
    float inv = 1.f / (red[0] + red[1] + red[2] + red[3]);
    #pragma unroll
    for (int k = 0; k < 8; ++k) ps[t + 256 * k] = vals[k] * inv;
    __syncthreads();

    const float* P = ps + chunk * 256 + w * 64;
    float acc = 0.f;
    #pragma unroll 4
    for (int k = 0; k < 64; ++k) {
        int c = chunk * 256 + w * 64 + k;
        acc += P[k] * bf2f(qkv[(size_t)(b * S_ + c) * 3072 + 2 * E_ + h * D_ + d]);
    }
    redv[w][d] = acc;
    __syncthreads();
    if (w == 0)
        atomicAdd(&gacc[tup * D_ + d], redv[0][d] + redv[1][d] + redv[2][d] + redv[3][d]);
}

__global__ __launch_bounds__(256)
void gattn_fin(const float* __restrict__ gacc, unsigned short* __restrict__ attn) {
    int gid = blockIdx.x * 256 + threadIdx.x;   // 4096
    int tup = gid >> 6, d = gid & 63;
    int b = tup >> 5, i = (tup >> 4) & 1, h = tup & 15;
    attn[(size_t)(b * S_ + i) * E_ + h * D_ + d] = f2bf(gacc[gid]);
}

extern "C" void kernel_launch(void* const* d_in, const int* in_sizes, int n_in,
                              void* d_out, int out_size, void* d_ws, size_t ws_size,
                              hipStream_t stream) {
    const float* x   = (const float*)d_in[0];
    const int*   rnd = (const int*)d_in[1];
    const float* qw  = (const float*)d_in[2];
    const float* qb  = (const float*)d_in[3];
    const float* kw  = (const float*)d_in[4];
    const float* kb  = (const float*)d_in[5];
    const float* vw  = (const float*)d_in[6];
    const float* vb  = (const float*)d_in[7];
    const float* ow  = (const float*)d_in[8];
    const float* ob  = (const float*)d_in[9];
    float* out = (float*)d_out;

    char* ws = (char*)d_ws;
    unsigned short* xb    = (unsigned short*)(ws);                       // 8 MB (dead after QKV GEMM)
    unsigned short* wqkv  = (unsigned short*)(ws + 8388608);             // 6 MB
    unsigned short* wo    = (unsigned short*)(ws + 14680064);            // 2 MB
    unsigned short* qkv   = (unsigned short*)(ws + 16777216);            // 24 MB
    unsigned short* attn  = (unsigned short*)(ws + 41943040);            // 8 MB
    float*          gsc   = (float*)(ws);                                // 512 KB (overlaps dead xb)
    float*          gacc  = (float*)(ws + 524288);                       // 16 KB

    const int M = B_ * S_;   // 4096

    {
        int total4 = (M * E_ + 4 * E_ * E_) / 4;
        convert_all<<<total4 / 256, 256, 0, stream>>>(x, qw, kw, vw, ow, xb, wqkv, wo);
    }

    // QKV GEMM: [4096][3072] bf16, BK=64 swizzled
    {
        dim3 grid(M / 128, 3 * E_ / 128);
        gemm_qkv<<<grid, 256, 0, stream>>>(xb, wqkv, qb, kb, vb, qkv, M, 3 * E_, E_);
    }

    // sparse rows + global-row scores (+ gacc zero), one dispatch
    attn_fused<<<1024 + 512, 256, 0, stream>>>(qkv, rnd, gsc, gacc, attn);

    // global-row PV (inline softmax) + finalize
    gattn_pv<<<dim3(B_ * NGLOB * H_, S_ / 256), 256, 0, stream>>>(qkv, gsc, gacc);
    gattn_fin<<<(B_ * NGLOB * H_ * D_) / 256, 256, 0, stream>>>(gacc, attn);

    // O GEMM -> fp32 out (BK=64 swizzled)
    {
        dim3 grid(M / 128, E_ / 64);
        gemm_o64<<<grid, 256, 0, stream>>>(attn, wo, ob, out, M, E_, E_);
    }
}

// Round 12
// 170.401 us; speedup vs baseline: 1.0770x; 1.0171x over previous
//
#include <hip/hip_runtime.h>

#define B_  2
#define S_  2048
#define E_  1024
#define H_  16
#define D_  64
#define NGLOB 2
#define NRAND 3
#define WIN 3

typedef __bf16 bf16x8 __attribute__((ext_vector_type(8)));
typedef float  f32x4  __attribute__((ext_vector_type(4)));

__device__ __forceinline__ unsigned short f2bf(float f) {
    unsigned u = __builtin_bit_cast(unsigned, f);
    unsigned r = u + 0x7FFFu + ((u >> 16) & 1u);   // RNE
    return (unsigned short)(r >> 16);
}
__device__ __forceinline__ float bf2f(unsigned short u) {
    return __builtin_bit_cast(float, (unsigned)u << 16);
}

// async global->LDS 16B DMA. LDS dest is wave-uniform base + lane*16.
__device__ __forceinline__ void g2l16(const unsigned short* g, unsigned short* l) {
    __builtin_amdgcn_global_load_lds(
        (const __attribute__((address_space(1))) unsigned*)g,
        (__attribute__((address_space(3))) unsigned*)l, 16, 0, 0);
}

// ---------------- fused fp32 -> bf16 conversion for x + 4 weights ----------------
__global__ __launch_bounds__(256)
void convert_all(const float* __restrict__ x,  const float* __restrict__ qw,
                 const float* __restrict__ kw, const float* __restrict__ vw,
                 const float* __restrict__ ow,
                 unsigned short* __restrict__ xb, unsigned short* __restrict__ wqkv,
                 unsigned short* __restrict__ wo) {
    const int XN = (B_ * S_ * E_) / 4;      // 1048576
    const int WN = (E_ * E_) / 4;           // 262144
    int i = blockIdx.x * blockDim.x + threadIdx.x;
    int r, loc;
    if (i < XN) { r = 0; loc = i; }
    else        { int j = i - XN; r = 1 + (j >> 18); loc = j & (WN - 1); }
    const float* src = r == 0 ? x : r == 1 ? qw : r == 2 ? kw : r == 3 ? vw : ow;
    float4 f = ((const float4*)src)[loc];
    ushort4 u;
    u.x = f2bf(f.x); u.y = f2bf(f.y); u.z = f2bf(f.z); u.w = f2bf(f.w);
    ushort4* dst = r == 0 ? (ushort4*)xb : r == 4 ? (ushort4*)wo
                 : (ushort4*)wqkv + (size_t)(r - 1) * WN;
    dst[loc] = u;
}

// ---------------- QKV GEMM: BK=64, XOR-swizzled LDS ----------------
// (256,3): 768-block grid fully resident in ONE round (256 CU x 3) — no tail.
// R7/R8/R9 difference-of-differences shows (256,3) itself was -1.4us; the R8
// regression was the fence-based finalize, not this bound. LDS 3x32=96KB ok.
__global__ __launch_bounds__(256, 3)
void gemm_qkv(const unsigned short* __restrict__ A,  // [M][K] bf16
              const unsigned short* __restrict__ W,  // [N][K] bf16
              const float* __restrict__ b0, const float* __restrict__ b1,
              const float* __restrict__ b2,
              unsigned short* __restrict__ Cb, int M, int N, int K) {
    __shared__ unsigned short sA[128 * 64];   // 16 KB
    __shared__ unsigned short sB[128 * 64];   // 16 KB
    const int t = threadIdx.x;
    const int lane = t & 63;
    const int wave = t >> 6;
    const int wm = wave >> 1, wn = wave & 1;
    const int lq = lane >> 4;
    const int lr = lane & 15;
    const int bm = blockIdx.x * 128;
    const int bn = blockIdx.y * 128;

    f32x4 acc[4][4] = {};

    for (int k0 = 0; k0 < K; k0 += 64) {
        const unsigned short* Abase = A + (size_t)bm * K + k0;
        const unsigned short* Wbase = W + (size_t)bn * K + k0;
        #pragma unroll
        for (int j = 0; j < 4; ++j) {             // 1024 chunks each
            int c = j * 256 + t;
            int row = c >> 3, cc = c & 7;
            int gcol = ((cc ^ (row & 7)) << 3);   // swizzled source col
            int dst = j * 2048 + wave * 512;      // wave-uniform elem offset
            g2l16(Abase + (size_t)row * K + gcol, sA + dst);
            g2l16(Wbase + (size_t)row * K + gcol, sB + dst);
        }
        __syncthreads();

        #pragma unroll
        for (int ks = 0; ks < 2; ++ks) {
            const int sw = (((ks << 2) + lq) ^ (lr & 7)) << 3;
            bf16x8 af[4], bfr[4];
            #pragma unroll
            for (int i = 0; i < 4; ++i)
                af[i] = *(const bf16x8*)&sA[(wm * 64 + i * 16 + lr) * 64 + sw];
            #pragma unroll
            for (int j = 0; j < 4; ++j)
                bfr[j] = *(const bf16x8*)&sB[(wn * 64 + j * 16 + lr) * 64 + sw];
            #pragma unroll
            for (int i = 0; i < 4; ++i)
                #pragma unroll
                for (int j = 0; j < 4; ++j)
                    acc[i][j] = __builtin_amdgcn_mfma_f32_16x16x32_bf16(af[i], bfr[j], acc[i][j], 0, 0, 0);
        }
        __syncthreads();
    }

    #pragma unroll
    for (int i = 0; i < 4; ++i) {
        int row0 = bm + wm * 64 + i * 16 + lq * 4;
        #pragma unroll
        for (int j = 0; j < 4; ++j) {
            int col = bn + wn * 64 + j * 16 + lr;
            const float* bp = col < E_ ? b0 : (col < 2 * E_ ? b1 : b2);
            float bv = bp[col & (E_ - 1)];
            #pragma unroll
            for (int r = 0; r < 4; ++r)
                Cb[(size_t)(row0 + r) * N + col] = f2bf(acc[i][j][r] + bv);
        }
    }
}

// ---------------- O GEMM: 128x64 tile, BK=64 XOR-swizzled ----------------
// A tile 128x64 = 1024 chunks (j<4); B tile 64x64 = 512 chunks (j<2).
__global__ __launch_bounds__(256, 2)
void gemm_o64(const unsigned short* __restrict__ A,
              const unsigned short* __restrict__ W,
              const float* __restrict__ bias,
              float* __restrict__ Cf, int M, int N, int K) {
    __shared__ unsigned short sA[128 * 64];   // 16 KB
    __shared__ unsigned short sB[64 * 64];    // 8 KB
    const int t = threadIdx.x;
    const int lane = t & 63;
    const int wave = t >> 6;
    const int lq = lane >> 4;
    const int lr = lane & 15;
    const int bm = blockIdx.x * 128;
    const int bn = blockIdx.y * 64;

    f32x4 acc[2][4] = {};

    for (int k0 = 0; k0 < K; k0 += 64) {
        const unsigned short* Abase = A + (size_t)bm * K + k0;
        const unsigned short* Wbase = W + (size_t)bn * K + k0;
        #pragma unroll
        for (int j = 0; j < 4; ++j) {           // A: 1024 chunks
            int c = j * 256 + t;
            int row = c >> 3, cc = c & 7;
            int gcol = ((cc ^ (row & 7)) << 3);
            int dst = j * 2048 + wave * 512;
            g2l16(Abase + (size_t)row * K + gcol, sA + dst);
        }
        #pragma unroll
        for (int j = 0; j < 2; ++j) {           // B: 512 chunks
            int c = j * 256 + t;
            int row = c >> 3, cc = c & 7;
            int gcol = ((cc ^ (row & 7)) << 3);
            int dst = j * 2048 + wave * 512;
            g2l16(Wbase + (size_t)row * K + gcol, sB + dst);
        }
        __syncthreads();

        #pragma unroll
        for (int ks = 0; ks < 2; ++ks) {
            const int sw = (((ks << 2) + lq) ^ (lr & 7)) << 3;
            bf16x8 af[2], bfr[4];
            #pragma unroll
            for (int i = 0; i < 2; ++i)
                af[i] = *(const bf16x8*)&sA[(wave * 32 + i * 16 + lr) * 64 + sw];
            #pragma unroll
            for (int j = 0; j < 4; ++j)
                bfr[j] = *(const bf16x8*)&sB[(j * 16 + lr) * 64 + sw];
            #pragma unroll
            for (int i = 0; i < 2; ++i)
                #pragma unroll
                for (int j = 0; j < 4; ++j)
                    acc[i][j] = __builtin_amdgcn_mfma_f32_16x16x32_bf16(af[i], bfr[j], acc[i][j], 0, 0, 0);
        }
        __syncthreads();
    }

    #pragma unroll
    for (int i = 0; i < 2; ++i) {
        int row0 = bm + wave * 32 + i * 16 + lq * 4;
        #pragma unroll
        for (int j = 0; j < 4; ++j) {
            int col = bn + j * 16 + lr;
            float bv = bias[col];
            #pragma unroll
            for (int r = 0; r < 4; ++r)
                Cf[(size_t)(row0 + r) * N + col] = acc[i][j][r] + bv;
        }
    }
}

// ---------------- fused: sparse rows (wave-per-row) + global-row scores ----------------
// grid = 1024 (sparse, XCD-swizzled) + 512 (gattn score chunks; seg==0 zeroes gacc)
__global__ __launch_bounds__(256)
void attn_fused(const unsigned short* __restrict__ qkv,
                const int* __restrict__ rnd,
                float* __restrict__ gsc, float* __restrict__ gacc,
                unsigned short* __restrict__ attn) {
    const int NB = B_ * (S_ - 2);     // 4092
    int t = threadIdx.x;

    if (blockIdx.x >= 1024) {
        // ---- global-row score chunk ----
        int bid2 = blockIdx.x - 1024;         // [0,512)
        int tup = bid2 >> 3, seg = bid2 & 7;
        int b = tup >> 5, i = (tup >> 4) & 1, h = tup & 15;
        __shared__ float qs[D_];
        if (t < D_) qs[t] = bf2f(qkv[(size_t)(b * S_ + i) * 3072 + h * D_ + t]);
        if (seg == 0 && t < D_) gacc[tup * D_ + t] = 0.f;
        __syncthreads();
        int c = seg * 256 + t;
        const bf16x8* kp = (const bf16x8*)(qkv + (size_t)(b * S_ + c) * 3072 + E_ + h * D_);
        float s = 0.f;
        #pragma unroll
        for (int w = 0; w < 8; ++w) {
            bf16x8 kv = kp[w];
            #pragma unroll
            for (int j = 0; j < 8; ++j) s += qs[w * 8 + j] * (float)kv[j];
        }
        gsc[(size_t)tup * S_ + c] = s * 0.125f;
        return;
    }

    // ---- sparse rows: one wave per row ----
    int bidx = (blockIdx.x & 7) * 128 + (blockIdx.x >> 3);   // XCD swizzle
    int w = t >> 6, l = t & 63;
    int row = bidx * 4 + w;
    bool valid = row < NB;
    int b = row / (S_ - 2);
    int i = row % (S_ - 2) + 2;
    if (!valid) { b = 0; i = 2; }

    __shared__ int   cols_s[4][12];
    __shared__ int   ncol_sh[4];
    __shared__ float pr_s[4][16 * 13 + 3];

    const bf16x8* qp = (const bf16x8*)(qkv + (size_t)(b * S_ + i) * 3072);
    bf16x8 q0 = qp[l * 2], q1 = qp[l * 2 + 1];
    float qreg[16];
    #pragma unroll
    for (int j = 0; j < 8; ++j) { qreg[j] = (float)q0[j]; qreg[8 + j] = (float)q1[j]; }

    if (l == 0) {
        int* cols = cols_s[w];
        int n = 0;
        cols[n++] = 0; cols[n++] = 1;
        int lo = i - WIN; if (lo < NGLOB) lo = NGLOB;
        int hi = i + WIN; if (hi > S_ - 1) hi = S_ - 1;
        for (int j = lo; j <= hi; ++j) cols[n++] = j;
        for (int r = 0; r < NRAND; ++r) {
            int c = rnd[i * NRAND + r];
            bool dup = false;
            for (int q = 0; q < n; ++q) dup = dup || (cols[q] == c);
            if (!dup) cols[n++] = c;
        }
        ncol_sh[w] = n;
        for (int q = n; q < 12; ++q) cols[q] = 0;
    }
    __syncthreads();
    const int n = ncol_sh[w];
    const int h4 = l >> 2;

    float sco[12];
    #pragma unroll
    for (int c = 0; c < 12; ++c) {
        const bf16x8* kp = (const bf16x8*)(qkv + (size_t)(b * S_ + cols_s[w][c]) * 3072 + E_);
        bf16x8 k0 = kp[l * 2], k1 = kp[l * 2 + 1];
        float s = 0.f;
        #pragma unroll
        for (int j = 0; j < 8; ++j) s += qreg[j] * (float)k0[j] + qreg[8 + j] * (float)k1[j];
        s += __shfl_xor(s, 1);
        s += __shfl_xor(s, 2);
        sco[c] = (c < n) ? s * 0.125f : -1e30f;
    }

    if ((l & 3) == 0) {
        float m = -1e30f;
        #pragma unroll
        for (int c = 0; c < 12; ++c) m = fmaxf(m, sco[c]);
        float sum = 0.f;
        #pragma unroll
        for (int c = 0; c < 12; ++c) { float e = __expf(sco[c] - m); sco[c] = e; sum += e; }
        float inv = 1.f / sum;
        #pragma unroll
        for (int c = 0; c < 12; ++c) pr_s[w][h4 * 13 + c] = sco[c] * inv;
    }
    __syncthreads();

    float o[16] = {};
    #pragma unroll
    for (int c = 0; c < 12; ++c) {
        float p = pr_s[w][h4 * 13 + c];
        const bf16x8* vp = (const bf16x8*)(qkv + (size_t)(b * S_ + cols_s[w][c]) * 3072 + 2 * E_);
        bf16x8 v0 = vp[l * 2], v1 = vp[l * 2 + 1];
        #pragma unroll
        for (int j = 0; j < 8; ++j) { o[j] += p * (float)v0[j]; o[8 + j] += p * (float)v1[j]; }
    }

    if (valid) {
        ushort4 u0, u1, u2, u3;
        u0.x = f2bf(o[0]);  u0.y = f2bf(o[1]);  u0.z = f2bf(o[2]);  u0.w = f2bf(o[3]);
        u1.x = f2bf(o[4]);  u1.y = f2bf(o[5]);  u1.z = f2bf(o[6]);  u1.w = f2bf(o[7]);
        u2.x = f2bf(o[8]);  u2.y = f2bf(o[9]);  u2.z = f2bf(o[10]); u2.w = f2bf(o[11]);
        u3.x = f2bf(o[12]); u3.y = f2bf(o[13]); u3.z = f2bf(o[14]); u3.w = f2bf(o[15]);
        ushort4* op = (ushort4*)(attn + (size_t)(b * S_ + i) * E_ + l * 16);
        op[0] = u0; op[1] = u1; op[2] = u2; op[3] = u3;
    }
}

// ---------------- global-row PV with inline softmax (no fences) ----------------
__global__ __launch_bounds__(256)
void gattn_pv(const unsigned short* __restrict__ qkv, const float* __restrict__ gsc,
              float* __restrict__ gacc) {
    int tup = blockIdx.x, chunk = blockIdx.y;
    int b = tup >> 5, h = tup & 15;
    int t = threadIdx.x, w = t >> 6, d = t & 63;
    __shared__ float ps[S_];          // probs, 8 KB
    __shared__ float red[4];
    __shared__ float redv[4][D_];
    const float* sc = gsc + (size_t)tup * S_;

    float vals[8];
    float m = -1e30f;
    #pragma unroll
    for (int k = 0; k < 8; ++k) { vals[k] = sc[t + 256 * k]; m = fmaxf(m, vals[k]); }
    #pragma unroll
    for (int o = 32; o; o >>= 1) m = fmaxf(m, __shfl_down(m, o));
    if ((t & 63) == 0) red[t >> 6] = m;
    __syncthreads();
    m = fmaxf(fmaxf(red[0], red[1]), fmaxf(red[2], red[3]));
    __syncthreads();
    float sum = 0.f;
    #pragma unroll
    for (int k = 0; k < 8; ++k) { float e = __expf(vals[k] - m); vals[k] = e; sum += e; }
    #pragma unroll
    for (int o = 32; o; o >>= 1) sum += __shfl_down(sum, o);
    if ((t & 63) == 0) red[t >> 6] = sum;
    __syncthreads();
    float inv = 1.f / (red[0] + red[1] + red[2] + red[3]);
    #pragma unroll
    for (int k = 0; k < 8; ++k) ps[t + 256 * k] = vals[k] * inv;
    __syncthreads();

    const float* P = ps + chunk * 256 + w * 64;
    float acc = 0.f;
    #pragma unroll 4
    for (int k = 0; k < 64; ++k) {
        int c = chunk * 256 + w * 64 + k;
        acc += P[k] * bf2f(qkv[(size_t)(b * S_ + c) * 3072 + 2 * E_ + h * D_ + d]);
    }
    redv[w][d] = acc;
    __syncthreads();
    if (w == 0)
        atomicAdd(&gacc[tup * D_ + d], redv[0][d] + redv[1][d] + redv[2][d] + redv[3][d]);
}

__global__ __launch_bounds__(256)
void gattn_fin(const float* __restrict__ gacc, unsigned short* __restrict__ attn) {
    int gid = blockIdx.x * 256 + threadIdx.x;   // 4096
    int tup = gid >> 6, d = gid & 63;
    int b = tup >> 5, i = (tup >> 4) & 1, h = tup & 15;
    attn[(size_t)(b * S_ + i) * E_ + h * D_ + d] = f2bf(gacc[gid]);
}

extern "C" void kernel_launch(void* const* d_in, const int* in_sizes, int n_in,
                              void* d_out, int out_size, void* d_ws, size_t ws_size,
                              hipStream_t stream) {
    const float* x   = (const float*)d_in[0];
    const int*   rnd = (const int*)d_in[1];
    const float* qw  = (const float*)d_in[2];
    const float* qb  = (const float*)d_in[3];
    const float* kw  = (const float*)d_in[4];
    const float* kb  = (const float*)d_in[5];
    const float* vw  = (const float*)d_in[6];
    const float* vb  = (const float*)d_in[7];
    const float* ow  = (const float*)d_in[8];
    const float* ob  = (const float*)d_in[9];
    float* out = (float*)d_out;

    char* ws = (char*)d_ws;
    unsigned short* xb    = (unsigned short*)(ws);                       // 8 MB (dead after QKV GEMM)
    unsigned short* wqkv  = (unsigned short*)(ws + 8388608);             // 6 MB
    unsigned short* wo    = (unsigned short*)(ws + 14680064);            // 2 MB
    unsigned short* qkv   = (unsigned short*)(ws + 16777216);            // 24 MB
    unsigned short* attn  = (unsigned short*)(ws + 41943040);            // 8 MB
    float*          gsc   = (float*)(ws);                                // 512 KB (overlaps dead xb)
    float*          gacc  = (float*)(ws + 524288);                       // 16 KB

    const int M = B_ * S_;   // 4096

    {
        int total4 = (M * E_ + 4 * E_ * E_) / 4;
        convert_all<<<total4 / 256, 256, 0, stream>>>(x, qw, kw, vw, ow, xb, wqkv, wo);
    }

    // QKV GEMM: [4096][3072] bf16, BK=64 swizzled, fully-resident grid
    {
        dim3 grid(M / 128, 3 * E_ / 128);
        gemm_qkv<<<grid, 256, 0, stream>>>(xb, wqkv, qb, kb, vb, qkv, M, 3 * E_, E_);
    }

    // sparse rows + global-row scores (+ gacc zero), one dispatch
    attn_fused<<<1024 + 512, 256, 0, stream>>>(qkv, rnd, gsc, gacc, attn);

    // global-row PV (inline softmax) + finalize
    gattn_pv<<<dim3(B_ * NGLOB * H_, S_ / 256), 256, 0, stream>>>(qkv, gsc, gacc);
    gattn_fin<<<(B_ * NGLOB * H_ * D_) / 256, 256, 0, stream>>>(gacc, attn);

    // O GEMM -> fp32 out (BK=64 swizzled)
    {
        dim3 grid(M / 128, E_ / 64);
        gemm_o64<<<grid, 256, 0, stream>>>(attn, wo, ob, out, M, E_, E_);
    }
}